// Round 1
// baseline (93.358 us; speedup 1.0000x reference)
//
#include <hip/hip_runtime.h>
#include <hip/hip_bf16.h>
#include <math.h>

#define B_   2
#define N_   512
#define FN   128
#define FE   16
#define MID_ 128

// monotonic f32 -> u32 encode for atomicMax-based float max
__device__ __forceinline__ unsigned enc_f32(float f) {
    unsigned u = __float_as_uint(f);
    return (u & 0x80000000u) ? ~u : (u | 0x80000000u);
}
__device__ __forceinline__ float dec_f32(unsigned u) {
    return (u & 0x80000000u) ? __uint_as_float(u ^ 0x80000000u) : __uint_as_float(~u);
}
#define ENC_NEG_INF 0x007FFFFFu   // enc(-inf)

// ---------------------------------------------------------------------------
// kA: msg1c = feat@W1 + b1 + (g@Wg + bg) + be ; msg2 = feat@W2 + b2 ;
//     h1 = feat@Wo1 + bo1 ; enc init.
// grid 128 (b x 64 n-tiles of 8 rows), block 128 (m)
// ---------------------------------------------------------------------------
__global__ __launch_bounds__(128) void kA(
    const float* __restrict__ feat, const float* __restrict__ gfeat,
    const float* __restrict__ W1, const float* __restrict__ b1,
    const float* __restrict__ W2, const float* __restrict__ b2,
    const float* __restrict__ be,
    const float* __restrict__ Wg, const float* __restrict__ bg,
    const float* __restrict__ Wo1, const float* __restrict__ bo1,
    float* __restrict__ msg1c, float* __restrict__ msg2,
    float* __restrict__ h1, unsigned* __restrict__ encb)
{
    __shared__ float fl[8 * 128];
    const int b  = blockIdx.x >> 6;
    const int n0 = (blockIdx.x & 63) * 8;
    const int t  = threadIdx.x;
    const float* fbase = feat + (size_t)(b * N_ + n0) * FN;
    for (int q = t; q < 256; q += 128)
        ((float4*)fl)[q] = ((const float4*)fbase)[q];
    __syncthreads();

    const int m = t;
    // msgg_c (per-thread redundant, 128 FMA)
    float mg = bg[m] + be[m];
    for (int k = 0; k < FN; ++k) mg += gfeat[b * FN + k] * Wg[k * MID_ + m];

    float a1[8], a2[8], a3[8];
    #pragma unroll
    for (int r = 0; r < 8; ++r) { a1[r] = 0.f; a2[r] = 0.f; a3[r] = 0.f; }
    for (int k = 0; k < FN; ++k) {
        const float w1 = W1[k * MID_ + m];
        const float w2 = W2[k * MID_ + m];
        const float w3 = Wo1[k * MID_ + m];
        #pragma unroll
        for (int r = 0; r < 8; ++r) {
            const float f = fl[r * 128 + k];
            a1[r] += f * w1; a2[r] += f * w2; a3[r] += f * w3;
        }
    }
    const float bb1 = b1[m], bb2 = b2[m], bb3 = bo1[m];
    #pragma unroll
    for (int r = 0; r < 8; ++r) {
        const size_t idx = (size_t)(b * N_ + n0 + r) * MID_ + m;
        msg1c[idx] = a1[r] + bb1 + mg;
        msg2[idx]  = a2[r] + bb2;
        h1[idx]    = a3[r] + bb3;
        encb[idx]  = ENC_NEG_INF;   // re-init every call (replay determinism)
    }
}

// ---------------------------------------------------------------------------
// kB: out_enc[b,j,m] = max_i adj[b,i,j] * (msg1c[b,j,m] + msg2[b,i,m]
//                                          + e_features[b,i,j,:] @ We[:,m])
// grid 512 = b(2) x jt(16) x ic(16); block 256 = 8 j-groups x 32 m-groups
// each thread: 4 j x 4 m, We columns in registers
// ---------------------------------------------------------------------------
__global__ __launch_bounds__(256) void kB(
    const float* __restrict__ ef, const float* __restrict__ adj,
    const float* __restrict__ We,
    const float* __restrict__ msg1c, const float* __restrict__ msg2,
    unsigned* __restrict__ encb)
{
    __shared__ float adj_l[32 * 32];     // [i_local][j_local]
    __shared__ float m2_l[32 * 128];     // [i_local][m]
    __shared__ float ef_l[32 * 16];      // [j_local][e]

    const int bid = blockIdx.x;
    const int b   = bid >> 8;
    const int jt  = (bid >> 4) & 15;
    const int ic  = bid & 15;
    const int j0  = jt * 32, i0 = ic * 32;
    const int t      = threadIdx.x;
    const int mt     = t & 31;
    const int jt_loc = t >> 5;
    const int m0     = mt * 4;

    // prestage adj chunk [32 i][32 j]
    {
        const int il = t >> 3, joff = (t & 7) * 4;
        const float* src = adj + (size_t)(b * N_ + i0 + il) * N_ + j0 + joff;
        *(float4*)&adj_l[il * 32 + joff] = *(const float4*)src;
    }
    // prestage msg2 chunk [32 i][128 m] (4096 contiguous floats)
    {
        const float4* src = (const float4*)(msg2 + (size_t)(b * N_ + i0) * MID_);
        float4* dst = (float4*)m2_l;
        for (int q = t; q < 1024; q += 256) dst[q] = src[q];
    }
    // We columns -> 64 VGPRs
    float4 we[16];
    #pragma unroll
    for (int e = 0; e < 16; ++e) we[e] = *(const float4*)&We[e * MID_ + m0];
    // C1 = msg1c rows for this thread's 4 j
    float4 c1[4];
    #pragma unroll
    for (int jj = 0; jj < 4; ++jj) {
        const int j = j0 + jt_loc + 8 * jj;
        c1[jj] = *(const float4*)&msg1c[(size_t)(b * N_ + j) * MID_ + m0];
    }
    float4 acc[4];
    #pragma unroll
    for (int jj = 0; jj < 4; ++jj)
        acc[jj] = make_float4(-INFINITY, -INFINITY, -INFINITY, -INFINITY);

    const float* efbase = ef + ((size_t)(b * N_ + i0) * N_ + j0) * FE;

    for (int il = 0; il < 32; ++il) {
        __syncthreads();   // previous compute done before overwrite (covers prestage on il=0)
        if (t < 128)
            ((float4*)ef_l)[t] = ((const float4*)(efbase + (size_t)il * N_ * FE))[t];
        __syncthreads();

        const float4 m2 = *(const float4*)&m2_l[il * 128 + m0];
        #pragma unroll
        for (int jj = 0; jj < 4; ++jj) {
            const int jl = jt_loc + 8 * jj;
            const float a = adj_l[il * 32 + jl];
            if (a != 0.0f) {   // uniform per 32-lane group -> real exec skip
                float4 v;
                v.x = c1[jj].x + m2.x; v.y = c1[jj].y + m2.y;
                v.z = c1[jj].z + m2.z; v.w = c1[jj].w + m2.w;
                const float4* efj = (const float4*)&ef_l[jl * 16];
                #pragma unroll
                for (int ee = 0; ee < 4; ++ee) {
                    const float4 e4 = efj[ee];
                    float4 w;
                    w = we[ee*4+0]; v.x += e4.x*w.x; v.y += e4.x*w.y; v.z += e4.x*w.z; v.w += e4.x*w.w;
                    w = we[ee*4+1]; v.x += e4.y*w.x; v.y += e4.y*w.y; v.z += e4.y*w.z; v.w += e4.y*w.w;
                    w = we[ee*4+2]; v.x += e4.z*w.x; v.y += e4.z*w.y; v.z += e4.z*w.z; v.w += e4.z*w.w;
                    w = we[ee*4+3]; v.x += e4.w*w.x; v.y += e4.w*w.y; v.z += e4.w*w.z; v.w += e4.w*w.w;
                }
                v.x *= a; v.y *= a; v.z *= a; v.w *= a;
                acc[jj].x = fmaxf(acc[jj].x, v.x);
                acc[jj].y = fmaxf(acc[jj].y, v.y);
                acc[jj].z = fmaxf(acc[jj].z, v.z);
                acc[jj].w = fmaxf(acc[jj].w, v.w);
            } else {
                acc[jj].x = fmaxf(acc[jj].x, 0.0f);
                acc[jj].y = fmaxf(acc[jj].y, 0.0f);
                acc[jj].z = fmaxf(acc[jj].z, 0.0f);
                acc[jj].w = fmaxf(acc[jj].w, 0.0f);
            }
        }
    }
    #pragma unroll
    for (int jj = 0; jj < 4; ++jj) {
        const int j = j0 + jt_loc + 8 * jj;
        unsigned* dst = encb + (size_t)(b * N_ + j) * MID_ + m0;
        atomicMax(dst + 0, enc_f32(acc[jj].x));
        atomicMax(dst + 1, enc_f32(acc[jj].y));
        atomicMax(dst + 2, enc_f32(acc[jj].z));
        atomicMax(dst + 3, enc_f32(acc[jj].w));
    }
}

// ---------------------------------------------------------------------------
// kC: out = h1 + dec(enc) @ Wo2 + bo2
// grid 128 (b x 64 j-tiles of 8), block 128 (o)
// ---------------------------------------------------------------------------
__global__ __launch_bounds__(128) void kC(
    const unsigned* __restrict__ encb, const float* __restrict__ h1,
    const float* __restrict__ Wo2, const float* __restrict__ bo2,
    float* __restrict__ out)
{
    __shared__ float ms[8 * 128];
    const int b  = blockIdx.x >> 6;
    const int j0 = (blockIdx.x & 63) * 8;
    const int t  = threadIdx.x;
    const unsigned* ebase = encb + (size_t)(b * N_ + j0) * MID_;
    #pragma unroll
    for (int r = 0; r < 8; ++r) ms[r * 128 + t] = dec_f32(ebase[r * 128 + t]);
    __syncthreads();

    const int o = t;
    const float bb = bo2[o];
    float acc[8];
    #pragma unroll
    for (int r = 0; r < 8; ++r)
        acc[r] = h1[(size_t)(b * N_ + j0 + r) * MID_ + o] + bb;
    for (int k = 0; k < MID_; ++k) {
        const float w = Wo2[k * MID_ + o];
        #pragma unroll
        for (int r = 0; r < 8; ++r) acc[r] += ms[r * 128 + k] * w;
    }
    #pragma unroll
    for (int r = 0; r < 8; ++r)
        out[(size_t)(b * N_ + j0 + r) * MID_ + o] = acc[r];
}

// ---------------------------------------------------------------------------
extern "C" void kernel_launch(void* const* d_in, const int* in_sizes, int n_in,
                              void* d_out, int out_size, void* d_ws, size_t ws_size,
                              hipStream_t stream)
{
    const float* feat = (const float*)d_in[0];
    const float* ef   = (const float*)d_in[1];
    const float* gf   = (const float*)d_in[2];
    const float* adj  = (const float*)d_in[3];
    const float* W1   = (const float*)d_in[4];
    const float* b1   = (const float*)d_in[5];
    const float* W2   = (const float*)d_in[6];
    const float* b2   = (const float*)d_in[7];
    const float* We   = (const float*)d_in[8];
    const float* be   = (const float*)d_in[9];
    const float* Wg   = (const float*)d_in[10];
    const float* bg   = (const float*)d_in[11];
    const float* Wo1  = (const float*)d_in[12];
    const float* bo1  = (const float*)d_in[13];
    const float* Wo2  = (const float*)d_in[14];
    const float* bo2  = (const float*)d_in[15];
    float* out = (float*)d_out;

    float* ws = (float*)d_ws;
    float*    msg1c = ws;                       // 131072 f32
    float*    msg2  = ws + 131072;              // 131072 f32
    float*    h1    = ws + 262144;              // 131072 f32
    unsigned* encb  = (unsigned*)(ws + 393216); // 131072 u32  (2 MB total)

    hipLaunchKernelGGL(kA, dim3(128), dim3(128), 0, stream,
        feat, gf, W1, b1, W2, b2, be, Wg, bg, Wo1, bo1, msg1c, msg2, h1, encb);
    hipLaunchKernelGGL(kB, dim3(512), dim3(256), 0, stream,
        ef, adj, We, msg1c, msg2, encb);
    hipLaunchKernelGGL(kC, dim3(128), dim3(128), 0, stream,
        encb, h1, Wo2, bo2, out);
}

// Round 2
// 36.954 us; speedup vs baseline: 2.5263x; 2.5263x over previous
//
#include <hip/hip_runtime.h>
#include <hip/hip_bf16.h>
#include <math.h>

#define B_   2
#define N_   512
#define FN   128
#define FE   16
#define MID_ 128

typedef __attribute__((ext_vector_type(8)))  short short8_t;
typedef __attribute__((ext_vector_type(16))) float f32x16;

__device__ __forceinline__ short f2bf(float f) {
    __bf16 h = (__bf16)f;                    // fptrunc -> RNE bf16
    return __builtin_bit_cast(short, h);
}
// monotonic f32 -> u32 encode (order-preserving); max in u32 domain == fmax
__device__ __forceinline__ unsigned enc_f32(float f) {
    unsigned u = __float_as_uint(f);
    return u ^ (0x80000000u | (unsigned)((int)u >> 31));
}
__device__ __forceinline__ float dec_f32(unsigned u) {
    unsigned m = (u & 0x80000000u) ? 0x80000000u : 0xFFFFFFFFu;
    return __uint_as_float(u ^ m);
}
#define ENC_NEG_INF 0x007FFFFFu

// ---------------------------------------------------------------------------
// kA: msg1c = feat@W1+b1+(g@Wg+bg)+be ; msg2 = feat@W2+b2 ; h1 = feat@Wo1+bo1
// grid 512 (b x 256 tiles of 2 rows), block 256: r = t>>7, m = t&127
// ---------------------------------------------------------------------------
__global__ __launch_bounds__(256) void kA(
    const float* __restrict__ feat, const float* __restrict__ gfeat,
    const float* __restrict__ W1, const float* __restrict__ b1,
    const float* __restrict__ W2, const float* __restrict__ b2,
    const float* __restrict__ be,
    const float* __restrict__ Wg, const float* __restrict__ bg,
    const float* __restrict__ Wo1, const float* __restrict__ bo1,
    float* __restrict__ msg1c, float* __restrict__ msg2, float* __restrict__ h1)
{
    __shared__ float fl[2 * 128];
    const int bid = blockIdx.x;
    const int b   = bid >> 8;
    const int n0  = (bid & 255) * 2;
    const int t   = threadIdx.x;
    const int r   = t >> 7, m = t & 127;

    const float* fbase = feat + (size_t)(b * N_ + n0) * FN;
    if (t < 64) ((float4*)fl)[t] = ((const float4*)fbase)[t];
    __syncthreads();

    float mg = bg[m] + be[m];
    for (int k = 0; k < FN; ++k) mg += gfeat[b * FN + k] * Wg[k * MID_ + m];

    float a1 = 0.f, a2 = 0.f, a3 = 0.f;
    for (int k = 0; k < FN; ++k) {
        const float f = fl[r * 128 + k];
        a1 += f * W1[k * MID_ + m];
        a2 += f * W2[k * MID_ + m];
        a3 += f * Wo1[k * MID_ + m];
    }
    const size_t idx = (size_t)(b * N_ + n0 + r) * MID_ + m;
    msg1c[idx] = a1 + b1[m] + mg;
    msg2[idx]  = a2 + b2[m];
    h1[idx]    = a3 + bo1[m];
}

// ---------------------------------------------------------------------------
// kB: partial[ic][b][j][m] = enc( max_{i in chunk} adj[b,i,j] *
//        (msg1c[b,j,m] + msg2[b,i,m] + ef[b,i,j,:]@We[:,m]) )
// MFMA 32x32x16 bf16: A = ef tile (32j x 16e), B = We (16e x 32m),
// C = msg1c + msg2 folded in. grid 256 = 2b x 16jt x 8ic, block 512 (8 waves),
// wave w: i's [i0+8w, i0+8w+8), all 4 m-tiles. Block LDS enc-atomicMax reduce.
// ---------------------------------------------------------------------------
__global__ __launch_bounds__(512, 2) void kB(
    const float* __restrict__ ef, const float* __restrict__ adj,
    const float* __restrict__ We,
    const float* __restrict__ msg1c, const float* __restrict__ msg2,
    unsigned* __restrict__ part)
{
    __shared__ float    adj_l[64 * 32];    // [i_local][j_local]
    __shared__ unsigned tile[32 * 128];    // enc-u32 reduce tile [j][m]

    const int bid = blockIdx.x;            // 256 = 2b * 16jt * 8ic
    const int b   = bid >> 7;
    const int jt  = (bid >> 3) & 15;
    const int ic  = bid & 7;
    const int j0  = jt * 32, i0 = ic * 64;
    const int t   = threadIdx.x;
    const int wid = t >> 6;
    const int g   = (t >> 5) & 1;          // lane>>5 within wave
    const int lm  = t & 31;                // MFMA col lane (m offset)

    // stage adj chunk [64 i][32 j]
    {
        const int il = t >> 3, joff = (t & 7) * 4;
        *(float4*)&adj_l[il * 32 + joff] =
            *(const float4*)(adj + (size_t)(b * N_ + i0 + il) * N_ + j0 + joff);
    }
    // init reduce tile to enc(-inf)
    #pragma unroll
    for (int q = 0; q < 8; ++q) tile[t + q * 512] = ENC_NEG_INF;

    // B fragments (We columns, bf16): lane holds We[k=8g+j, mt*32+lm]
    short8_t Bf[4];
    #pragma unroll
    for (int mt = 0; mt < 4; ++mt) {
        short8_t s;
        #pragma unroll
        for (int j = 0; j < 8; ++j)
            s[j] = f2bf(We[(8 * g + j) * MID_ + mt * 32 + lm]);
        Bf[mt] = s;
    }
    // c1 fragments: msg1c at (j = j0 + jrow(r,g), m = mt*32+lm)
    float c1f[4][16];
    #pragma unroll
    for (int mt = 0; mt < 4; ++mt)
        #pragma unroll
        for (int r = 0; r < 16; ++r) {
            const int jr = (r & 3) + 8 * (r >> 2) + 4 * g;
            c1f[mt][r] = msg1c[(size_t)(b * N_ + j0 + jr) * MID_ + mt * 32 + lm];
        }

    float accm[4][16];
    #pragma unroll
    for (int mt = 0; mt < 4; ++mt)
        #pragma unroll
        for (int r = 0; r < 16; ++r) accm[mt][r] = -INFINITY;

    __syncthreads();

    const int iw0 = i0 + wid * 8;
    for (int ii = 0; ii < 8; ++ii) {
        const int i  = iw0 + ii;
        const int il = wid * 8 + ii;
        // A fragment: lane holds ef[b, i, j0+lm, e = 8g..8g+7]
        const float* efr = ef + ((size_t)(b * N_ + i) * N_ + j0 + lm) * FE + 8 * g;
        const float4 ea = *(const float4*)efr;
        const float4 eb = *(const float4*)(efr + 4);
        short8_t Af;
        Af[0] = f2bf(ea.x); Af[1] = f2bf(ea.y); Af[2] = f2bf(ea.z); Af[3] = f2bf(ea.w);
        Af[4] = f2bf(eb.x); Af[5] = f2bf(eb.y); Af[6] = f2bf(eb.z); Af[7] = f2bf(eb.w);
        // adj factors for this i (reused across m-tiles); broadcast LDS reads
        float af[16];
        #pragma unroll
        for (int r = 0; r < 16; ++r)
            af[r] = adj_l[il * 32 + (r & 3) + 8 * (r >> 2) + 4 * g];

        #pragma unroll
        for (int mt = 0; mt < 4; ++mt) {
            const float m2v = msg2[(size_t)(b * N_ + i) * MID_ + mt * 32 + lm];
            f32x16 C;
            #pragma unroll
            for (int r = 0; r < 16; ++r) C[r] = c1f[mt][r] + m2v;
            const f32x16 S = __builtin_amdgcn_mfma_f32_32x32x16_bf16(Af, Bf[mt], C, 0, 0, 0);
            #pragma unroll
            for (int r = 0; r < 16; ++r)
                accm[mt][r] = fmaxf(accm[mt][r], S[r] * af[r]);
        }
    }

    // cross-wave reduce: enc + LDS atomicMax (order-independent, deterministic)
    #pragma unroll
    for (int mt = 0; mt < 4; ++mt)
        #pragma unroll
        for (int r = 0; r < 16; ++r) {
            const int idx = ((r & 3) + 8 * (r >> 2) + 4 * g) * MID_ + mt * 32 + lm;
            atomicMax(&tile[idx], enc_f32(accm[mt][r]));
        }
    __syncthreads();

    // store enc-u32 partial tile (4096 words, contiguous)
    unsigned* dst = part + ((size_t)(ic * 2 + b) * N_ + j0) * MID_;
    #pragma unroll
    for (int q = 0; q < 2; ++q)
        ((uint4*)dst)[t * 2 + q] = ((const uint4*)tile)[t * 2 + q];
}

// ---------------------------------------------------------------------------
// kC: msgs[b,j,m] = dec(max over 8 partials); out = h1 + msgs@Wo2 + bo2
// grid 512 (b x 256 tiles of 2 rows), block 256: r = t>>7, o = t&127
// ---------------------------------------------------------------------------
__global__ __launch_bounds__(256) void kC(
    const unsigned* __restrict__ part, const float* __restrict__ h1,
    const float* __restrict__ Wo2, const float* __restrict__ bo2,
    float* __restrict__ out)
{
    __shared__ float ms[2 * 128];
    const int bid = blockIdx.x;
    const int b   = bid >> 8;
    const int j0  = (bid & 255) * 2;
    const int t   = threadIdx.x;
    const int r   = t >> 7, m = t & 127;
    const int j   = j0 + r;

    unsigned u = ENC_NEG_INF;
    #pragma unroll
    for (int icc = 0; icc < 8; ++icc) {
        const unsigned p = part[((size_t)(icc * 2 + b) * N_ + j) * MID_ + m];
        u = (p > u) ? p : u;
    }
    ms[r * 128 + m] = dec_f32(u);
    __syncthreads();

    const int o = m;
    float acc = h1[(size_t)(b * N_ + j) * MID_ + o] + bo2[o];
    for (int k = 0; k < MID_; ++k)
        acc += ms[r * 128 + k] * Wo2[k * MID_ + o];
    out[(size_t)(b * N_ + j) * MID_ + o] = acc;
}

// ---------------------------------------------------------------------------
extern "C" void kernel_launch(void* const* d_in, const int* in_sizes, int n_in,
                              void* d_out, int out_size, void* d_ws, size_t ws_size,
                              hipStream_t stream)
{
    const float* feat = (const float*)d_in[0];
    const float* ef   = (const float*)d_in[1];
    const float* gf   = (const float*)d_in[2];
    const float* adj  = (const float*)d_in[3];
    const float* W1   = (const float*)d_in[4];
    const float* b1   = (const float*)d_in[5];
    const float* W2   = (const float*)d_in[6];
    const float* b2   = (const float*)d_in[7];
    const float* We   = (const float*)d_in[8];
    const float* be   = (const float*)d_in[9];
    const float* Wg   = (const float*)d_in[10];
    const float* bg   = (const float*)d_in[11];
    const float* Wo1  = (const float*)d_in[12];
    const float* bo1  = (const float*)d_in[13];
    const float* Wo2  = (const float*)d_in[14];
    const float* bo2  = (const float*)d_in[15];
    float* out = (float*)d_out;

    float*    ws    = (float*)d_ws;
    float*    msg1c = ws;                        // 131072 f32
    float*    msg2  = ws + 131072;               // 131072 f32
    float*    h1    = ws + 262144;               // 131072 f32
    unsigned* part  = (unsigned*)(ws + 393216);  // 8*2*512*128 u32 = 4 MB

    hipLaunchKernelGGL(kA, dim3(512), dim3(256), 0, stream,
        feat, gf, W1, b1, W2, b2, be, Wg, bg, Wo1, bo1, msg1c, msg2, h1);
    hipLaunchKernelGGL(kB, dim3(256), dim3(512), 0, stream,
        ef, adj, We, msg1c, msg2, part);
    hipLaunchKernelGGL(kC, dim3(512), dim3(256), 0, stream,
        part, h1, Wo2, bo2, out);
}